// Round 5
// baseline (285.984 us; speedup 1.0000x reference)
//
#include <hip/hip_runtime.h>

typedef unsigned short u16;
typedef unsigned int u32;
using s16x8 = __attribute__((ext_vector_type(8))) short;
using s16x4 = __attribute__((ext_vector_type(4))) short;
using u16x4 = __attribute__((ext_vector_type(4))) unsigned short;
using u32x4 = __attribute__((ext_vector_type(4))) unsigned int;
using f32x4 = __attribute__((ext_vector_type(4))) float;

__device__ __forceinline__ u16 f2bf(float f) {
  unsigned int u = __float_as_uint(f);
  u += 0x7FFFu + ((u >> 16) & 1u);
  return (u16)(u >> 16);
}
__device__ __forceinline__ float bf2f(u16 b) {
  return __uint_as_float(((u32)b) << 16);
}
__device__ __forceinline__ u32 pkbf(float a, float b) {
  u32 r;
  asm("v_cvt_pk_bf16_f32 %0, %1, %2" : "=v"(r) : "v"(a), "v"(b));
  return r;
}
// monotone 16-bit key from f32 (sign-flip trick, truncated)
__device__ __forceinline__ u32 f2key(float f) {
  u32 u = __float_as_uint(f);
  u32 flip = (u32)((int)u >> 31) | 0x80000000u;
  return (u ^ flip) >> 16;
}
// inverse: 16-bit key -> f32 (truncated value)
__device__ __forceinline__ float key2f(u32 k) {
  u32 t = k << 16;
  u32 msk = ((int)t < 0) ? 0x80000000u : 0xFFFF0000u;
  return __uint_as_float(t ^ msk);
}

// ---------------- weight transposes (f32 -> bf16, (in,out) -> (out,in)) ----------------
__global__ __launch_bounds__(256) void prep_w(
    const float* __restrict__ Wq, const float* __restrict__ Wk, const float* __restrict__ Wv,
    const float* __restrict__ Wo, const float* __restrict__ A1, const float* __restrict__ B1,
    const float* __restrict__ A2, const float* __restrict__ B2,
    u16* __restrict__ WqT, u16* __restrict__ WkT, u16* __restrict__ WvT, u16* __restrict__ WoT,
    u16* __restrict__ A1T, u16* __restrict__ B1T, u16* __restrict__ A2T, u16* __restrict__ B2T) {
  int b = blockIdx.x, t = threadIdx.x;
  const float* src; u16* dst; int base, R, C;
  if (b < 1024)      { src = Wq; dst = WqT; base = 0;    R = 512;  C = 512; }
  else if (b < 2048) { src = Wk; dst = WkT; base = 1024; R = 512;  C = 512; }
  else if (b < 3072) { src = Wv; dst = WvT; base = 2048; R = 512;  C = 512; }
  else if (b < 4096) { src = Wo; dst = WoT; base = 3072; R = 512;  C = 512; }
  else if (b < 4224) { src = A1; dst = A1T; base = 4096; R = 512;  C = 64;  }
  else if (b < 4736) { src = B1; dst = B1T; base = 4224; R = 64;   C = 2048;}
  else if (b < 5248) { src = A2; dst = A2T; base = 4736; R = 2048; C = 64;  }
  else               { src = B2; dst = B2T; base = 5248; R = 64;   C = 512; }
  int idx = (b - base) * 256 + t;
  int r = idx / C, c = idx % C;
  dst[(size_t)c * R + r] = f2bf(src[idx]);
}

// ---------------- fused QKV projection from f32 inputs: 128x128 tiles, grid (4,64,3) ----
// z=0: Q (scaled 0.125, scatter [nh][l][d]); z=1: K ([nh][l][d]); z=2: V ([nh][d][l]).
__global__ __launch_bounds__(256, 4) void qkv_fused(
    const float* __restrict__ q, const float* __restrict__ k, const float* __restrict__ v,
    const u16* __restrict__ WqT, const u16* __restrict__ WkT, const u16* __restrict__ WvT,
    const float* __restrict__ bq, const float* __restrict__ bk, const float* __restrict__ bv,
    u16* __restrict__ Qw, u16* __restrict__ Kw, u16* __restrict__ Vw) {
  __shared__ __align__(16) u16 As[128][72];
  __shared__ __align__(16) u16 Bs[128][72];
  const int z = blockIdx.z;
  const float* A = z == 0 ? q : (z == 1 ? k : v);
  const u16* Bt = z == 0 ? WqT : (z == 1 ? WkT : WvT);
  const float* bias = z == 0 ? bq : (z == 1 ? bk : bv);
  u16* outp = z == 0 ? Qw : (z == 1 ? Kw : Vw);

  const int tid = threadIdx.x;
  const int m0 = blockIdx.y * 128, n0 = blockIdx.x * 128;
  const int lane = tid & 63, wid = tid >> 6;
  const int l16 = lane & 15, hi = lane >> 4;
  const int wr = (wid >> 1) * 64, wc = (wid & 1) * 64;

  f32x4 acc[4][4];
#pragma unroll
  for (int i = 0; i < 4; ++i)
#pragma unroll
    for (int j = 0; j < 4; ++j) acc[i][j] = (f32x4){0.f, 0.f, 0.f, 0.f};

  for (int k0 = 0; k0 < 512; k0 += 64) {
    if (k0) __syncthreads();
#pragma unroll
    for (int i = 0; i < 4; ++i) {
      int idx = i * 256 + tid;
      int r = idx >> 3, cc = (idx & 7) * 8;
      float4 f0 = *(const float4*)&A[(size_t)(m0 + r) * 512 + k0 + cc];
      float4 f1 = *(const float4*)&A[(size_t)(m0 + r) * 512 + k0 + cc + 4];
      u32x4 pk;
      pk[0] = pkbf(f0.x, f0.y); pk[1] = pkbf(f0.z, f0.w);
      pk[2] = pkbf(f1.x, f1.y); pk[3] = pkbf(f1.z, f1.w);
      *(u32x4*)&As[r][cc] = pk;
      *(s16x8*)&Bs[r][cc] = *(const s16x8*)&Bt[(size_t)(n0 + r) * 512 + k0 + cc];
    }
    __syncthreads();
#pragma unroll
    for (int kk = 0; kk < 2; ++kk) {
      const int kb_ = kk * 32 + hi * 8;
      s16x8 af[4], bf[4];
#pragma unroll
      for (int mf = 0; mf < 4; ++mf) af[mf] = *(const s16x8*)&As[wr + mf * 16 + l16][kb_];
#pragma unroll
      for (int nf = 0; nf < 4; ++nf) bf[nf] = *(const s16x8*)&Bs[wc + nf * 16 + l16][kb_];
#pragma unroll
      for (int mf = 0; mf < 4; ++mf)
#pragma unroll
        for (int nf = 0; nf < 4; ++nf)
          acc[mf][nf] = __builtin_amdgcn_mfma_f32_16x16x32_bf16(af[mf], bf[nf], acc[mf][nf], 0, 0, 0);
    }
  }

#pragma unroll
  for (int mf = 0; mf < 4; ++mf)
#pragma unroll
    for (int nf = 0; nf < 4; ++nf)
#pragma unroll
      for (int i = 0; i < 4; ++i) {
        int row = m0 + wr + mf * 16 + hi * 4 + i;
        int col = n0 + wc + nf * 16 + l16;
        float val = acc[mf][nf][i] + bias[col];
        if (z == 0) val *= 0.125f;  // fold 1/sqrt(Dh) into Q
        int l = row >> 3, n = row & 7, hh = col >> 6, d = col & 63;
        if (z < 2)
          outp[(((size_t)(n * 8 + hh) * 1024 + l) << 6) + d] = f2bf(val);
        else
          outp[((size_t)(n * 8 + hh) * 64 + d) * 1024 + l] = f2bf(val);
      }
}

// ---------------- fused attention: QK^T -> top-k mask -> softmax -> PV ----------------
// grid (L/32, 64), 512 threads (8 waves). Qw (pre-scaled)/Kw: [nh][l][64]. Vw: [nh][64][1024].
// ao out: [t][d*8+h] bf16, t = l*8+n.
__global__ __launch_bounds__(512, 4) void attn_kernel(const u16* __restrict__ Qw,
                                                      const u16* __restrict__ Kw,
                                                      const u16* __restrict__ Vw,
                                                      const float* __restrict__ topk,
                                                      u16* __restrict__ ao) {
  __shared__ __align__(16) u16 scb[32 * 1024];  // 64KB: keys -> P (bf16), XOR-swizzled
  __shared__ __align__(16) u16 Qt[32][72];
  __shared__ float invs[32];
  const int tid = threadIdx.x, lane = tid & 63, wid = tid >> 6;
  const int l16 = lane & 15, hi = lane >> 4;
  const int mb = blockIdx.x, nh = blockIdx.y;

  const int kkeep = (int)(1024.f / (1.f + __expf(-topk[0])));

  // stage Q tile (32 x 64)
  {
    int r = tid >> 4, dc = (tid & 15) << 2;
    *(s16x4*)&Qt[r][dc] =
        *(const s16x4*)&Qw[((size_t)nh * 1024 + mb * 32 + r) * 64 + dc];
  }
  __syncthreads();

  // ---- Phase A: keys = key(QK^T). swapped mfma(K,Q): lane's 4 acc vals are
  // consecutive s for one q-row. Wave w covers s in [128w, 128w+128).
  {
    const u16* Kb = Kw + (size_t)nh * 1024 * 64;
    s16x8 bq0[2], bq1[2];
#pragma unroll
    for (int qh = 0; qh < 2; ++qh) {
      bq0[qh] = *(const s16x8*)&Qt[qh * 16 + l16][hi * 8];
      bq1[qh] = *(const s16x8*)&Qt[qh * 16 + l16][32 + hi * 8];
    }
    const int s0 = wid * 128;
#pragma unroll
    for (int nf = 0; nf < 8; ++nf) {
      const int sr = s0 + nf * 16 + l16;
      s16x8 a0 = *(const s16x8*)&Kb[(size_t)sr * 64 + hi * 8];
      s16x8 a1 = *(const s16x8*)&Kb[(size_t)sr * 64 + 32 + hi * 8];
#pragma unroll
      for (int qh = 0; qh < 2; ++qh) {
        f32x4 acc = {0.f, 0.f, 0.f, 0.f};
        acc = __builtin_amdgcn_mfma_f32_16x16x32_bf16(a0, bq0[qh], acc, 0, 0, 0);
        acc = __builtin_amdgcn_mfma_f32_16x16x32_bf16(a1, bq1[qh], acc, 0, 0, 0);
        const int row_q = qh * 16 + l16;
        u32 k0 = f2key(acc[0]) | (f2key(acc[1]) << 16);
        u32 k1 = f2key(acc[2]) | (f2key(acc[3]) << 16);
        char* rowq = (char*)scb + row_q * 2048;
        int boff = (2 * (s0 + nf * 16 + 4 * hi)) ^ ((row_q & 7) << 4);
        *(uint2*)(rowq + boff) = make_uint2(k0, k1);
      }
    }
  }
  __syncthreads();

  // ---- Phase B: whole wave owns one row (16 keys/lane); radix search via
  // ballot + scalar popcount (no shuffles, count lives in SGPRs); softmax shift
  // = threshold value itself (max-T bounded, exp stays finite). 2 rows in flight.
  {
#pragma unroll
    for (int rp = 0; rp < 2; ++rp) {
      const int r0 = wid * 4 + rp * 2, r1 = r0 + 1;
      char* rb0 = (char*)scb + r0 * 2048;
      char* rb1 = (char*)scb + r1 * 2048;
      const int X0 = (r0 & 7) << 4, X1 = (r1 & 7) << 4;
      u32 ka[16], kb_[16];
#pragma unroll
      for (int c = 0; c < 8; ++c) {
        u32 wa = *(const u32*)(rb0 + ((4 * lane + 256 * c) ^ X0));
        u32 wb = *(const u32*)(rb1 + ((4 * lane + 256 * c) ^ X1));
        ka[2 * c] = wa & 0xFFFFu; ka[2 * c + 1] = wa >> 16;
        kb_[2 * c] = wb & 0xFFFFu; kb_[2 * c + 1] = wb >> 16;
      }
      u32 Ta = 0, Tb = 0;
#pragma unroll
      for (int bit = 15; bit >= 0; --bit) {
        u32 ca = Ta + (1u << bit), cb = Tb + (1u << bit);
        int na = 0, nb = 0;
#pragma unroll
        for (int j = 0; j < 16; ++j) {
          na += __popcll(__ballot(ka[j] >= ca));
          nb += __popcll(__ballot(kb_[j] >= cb));
        }
        if (na >= kkeep) Ta = ca;
        if (nb >= kkeep) Tb = cb;
      }
      const float tva = key2f(Ta), tvb = key2f(Tb);
      float suma = 0.f, sumb = 0.f;
#pragma unroll
      for (int c = 0; c < 8; ++c) {
        float ea0, ea1, eb0, eb1;
        {
          u32 kk0 = ka[2 * c], kk1 = ka[2 * c + 1];
          float v0 = key2f(kk0), v1 = key2f(kk1);
          ea0 = (kk0 >= Ta) ? __expf(v0 - tva) : 0.f;
          ea1 = (kk1 >= Ta) ? __expf(v1 - tva) : 0.f;
          suma += ea0 + ea1;
        }
        {
          u32 kk0 = kb_[2 * c], kk1 = kb_[2 * c + 1];
          float v0 = key2f(kk0), v1 = key2f(kk1);
          eb0 = (kk0 >= Tb) ? __expf(v0 - tvb) : 0.f;
          eb1 = (kk1 >= Tb) ? __expf(v1 - tvb) : 0.f;
          sumb += eb0 + eb1;
        }
        *(u32*)(rb0 + ((4 * lane + 256 * c) ^ X0)) = pkbf(ea0, ea1);
        *(u32*)(rb1 + ((4 * lane + 256 * c) ^ X1)) = pkbf(eb0, eb1);
      }
#pragma unroll
      for (int off = 1; off < 64; off <<= 1) {
        suma += __shfl_xor(suma, off);
        sumb += __shfl_xor(sumb, off);
      }
      if (lane == 0) {
        invs[r0] = __builtin_amdgcn_rcpf(suma);
        invs[r1] = __builtin_amdgcn_rcpf(sumb);
      }
    }
  }
  __syncthreads();

  // ---- Phase C: out = (P @ V) * inv. wave w: rows [16*(w>>2)..+16), d [16*(w&3)..+16) ----
  {
    const u16* Vb = Vw + (size_t)nh * 64 * 1024;
    const int rh = wid >> 2, d0 = (wid & 3) * 16;
    f32x4 oacc0 = {0.f, 0.f, 0.f, 0.f};
    f32x4 oacc1 = {0.f, 0.f, 0.f, 0.f};
    const char* Pbase = (const char*)scb + (rh * 16 + l16) * 2048;
    const int Xp = (l16 & 7) << 4;
#pragma unroll
    for (int ks = 0; ks < 32; ks += 2) {
      int kb0 = (ks * 64 + hi * 16) ^ Xp;
      int kb1 = ((ks + 1) * 64 + hi * 16) ^ Xp;
      s16x8 a0 = *(const s16x8*)(Pbase + kb0);
      s16x8 a1 = *(const s16x8*)(Pbase + kb1);
      s16x8 b0 = *(const s16x8*)&Vb[(size_t)(d0 + l16) * 1024 + ks * 32 + hi * 8];
      s16x8 b1 = *(const s16x8*)&Vb[(size_t)(d0 + l16) * 1024 + (ks + 1) * 32 + hi * 8];
      oacc0 = __builtin_amdgcn_mfma_f32_16x16x32_bf16(a0, b0, oacc0, 0, 0, 0);
      oacc1 = __builtin_amdgcn_mfma_f32_16x16x32_bf16(a1, b1, oacc1, 0, 0, 0);
    }
    const int n = nh >> 3, hh = nh & 7;
#pragma unroll
    for (int i = 0; i < 4; ++i) {
      int l = mb * 32 + rh * 16 + hi * 4 + i;
      int d = d0 + l16;
      float vv = (oacc0[i] + oacc1[i]) * invs[rh * 16 + hi * 4 + i];
      ao[(size_t)(l * 8 + n) * 512 + d * 8 + hh] = f2bf(vv);
    }
  }
}

// ---------------- GEMM (BM=16, N=512, B direct from L2) + bias + resid + LayerNorm ----------------
// FIRST: out = LN1(ao@WoT + bo + q) -> srcb (bf16), K=512, residf=q
// else : out = LN2(w2@B2T + srcb)  -> d_out (f32), K=64, residb=srcb
template <bool FIRST>
__global__ __launch_bounds__(256, 2) void gemm_ln(const u16* __restrict__ A,
                                                  const u16* __restrict__ Bt,
                                                  const float* __restrict__ bias,
                                                  const float* __restrict__ residf,
                                                  const u16* __restrict__ residb,
                                                  const float* __restrict__ g,
                                                  const float* __restrict__ be,
                                                  float* __restrict__ outf,
                                                  u16* __restrict__ outb) {
  constexpr int K = FIRST ? 512 : 64;
  __shared__ __align__(16) u16 As[16][72];
  __shared__ float red_s[4][16];
  __shared__ float red_q[4][16];
  const int tid = threadIdx.x;
  const int lane = tid & 63, wid = tid >> 6;
  const int l16 = lane & 15, hi = lane >> 4;
  const int m0 = blockIdx.x * 16;
  const int wc = wid * 128;

  f32x4 acc[8];
#pragma unroll
  for (int nf = 0; nf < 8; ++nf) acc[nf] = (f32x4){0.f, 0.f, 0.f, 0.f};

  for (int k0 = 0; k0 < K; k0 += 64) {
    if (k0) __syncthreads();
    {
      int r = tid >> 4, c = (tid & 15) << 2;
      *(s16x4*)&As[r][c] = *(const s16x4*)&A[(size_t)(m0 + r) * K + k0 + c];
    }
    __syncthreads();
#pragma unroll
    for (int kk = 0; kk < 2; ++kk) {
      const int kb_ = kk * 32 + hi * 8;
      s16x8 a = *(const s16x8*)&As[l16][kb_];
#pragma unroll
      for (int nf = 0; nf < 8; ++nf) {
        s16x8 b = *(const s16x8*)&Bt[(size_t)(wc + nf * 16 + l16) * K + k0 + kb_];
        acc[nf] = __builtin_amdgcn_mfma_f32_16x16x32_bf16(a, b, acc[nf], 0, 0, 0);
      }
    }
  }

#pragma unroll
  for (int nf = 0; nf < 8; ++nf) {
    int col = wc + nf * 16 + l16;
#pragma unroll
    for (int i = 0; i < 4; ++i) {
      float v = acc[nf][i];
      int row = m0 + hi * 4 + i;
      if (FIRST) v += bias[col] + residf[(size_t)row * 512 + col];
      else v += bf2f(residb[(size_t)row * 512 + col]);
      acc[nf][i] = v;
    }
  }
  float s[4] = {0.f, 0.f, 0.f, 0.f}, q2[4] = {0.f, 0.f, 0.f, 0.f};
#pragma unroll
  for (int nf = 0; nf < 8; ++nf)
#pragma unroll
    for (int i = 0; i < 4; ++i) {
      s[i] += acc[nf][i];
      q2[i] += acc[nf][i] * acc[nf][i];
    }
#pragma unroll
  for (int i = 0; i < 4; ++i) {
#pragma unroll
    for (int off = 1; off < 16; off <<= 1) {
      s[i] += __shfl_xor(s[i], off);
      q2[i] += __shfl_xor(q2[i], off);
    }
  }
  if (l16 == 0) {
#pragma unroll
    for (int i = 0; i < 4; ++i) {
      red_s[wid][hi * 4 + i] = s[i];
      red_q[wid][hi * 4 + i] = q2[i];
    }
  }
  __syncthreads();
  float mean[4], rstd[4];
#pragma unroll
  for (int i = 0; i < 4; ++i) {
    int r = hi * 4 + i;
    float ms = red_s[0][r] + red_s[1][r] + red_s[2][r] + red_s[3][r];
    float mq = red_q[0][r] + red_q[1][r] + red_q[2][r] + red_q[3][r];
    mean[i] = ms * (1.f / 512.f);
    float var = mq * (1.f / 512.f) - mean[i] * mean[i];
    rstd[i] = rsqrtf(var + 1e-5f);
  }
#pragma unroll
  for (int nf = 0; nf < 8; ++nf) {
    int col = wc + nf * 16 + l16;
    float gv = g[col], bev = be[col];
#pragma unroll
    for (int i = 0; i < 4; ++i) {
      int row = m0 + hi * 4 + i;
      float y = (acc[nf][i] - mean[i]) * rstd[i] * gv + bev;
      if (FIRST) outb[(size_t)row * 512 + col] = f2bf(y);
      else outf[(size_t)row * 512 + col] = y;
    }
  }
}

// ---------------- fused low-rank FFN: w2 = relu(src@A1 @ B1) @ A2 ----------------
__global__ __launch_bounds__(256, 4) void ffn3(const u16* __restrict__ srcb,
                                               const u16* __restrict__ A1T,
                                               const u16* __restrict__ B1T,
                                               const u16* __restrict__ A2T,
                                               u16* __restrict__ w2) {
  __shared__ __align__(16) u16 As[32][72];
  __shared__ __align__(16) u16 Bs[64][72];
  __shared__ __align__(16) u16 Us[32][72];
  __shared__ __align__(16) u16 B1s[64][72];
  __shared__ __align__(16) u16 A2s[64][72];
  __shared__ __align__(16) u16 Hs[32][72];
  const int tid = threadIdx.x;
  const int lane = tid & 63, wid = tid >> 6;
  const int l16 = lane & 15, hi = lane >> 4;
  const int m0 = blockIdx.x * 32;
  const int wm = (wid & 1) * 16, wn = (wid >> 1) * 32;

  f32x4 accu[2];
  accu[0] = (f32x4){0.f, 0.f, 0.f, 0.f};
  accu[1] = (f32x4){0.f, 0.f, 0.f, 0.f};
  for (int k0 = 0; k0 < 512; k0 += 64) {
    if (k0) __syncthreads();
    {
      int r = tid >> 3, c = (tid & 7) << 3;
      *(s16x8*)&As[r][c] = *(const s16x8*)&srcb[(size_t)(m0 + r) * 512 + k0 + c];
    }
#pragma unroll
    for (int i = 0; i < 2; ++i) {
      int idx = i * 256 + tid;
      int r = idx >> 3, c = (idx & 7) << 3;
      *(s16x8*)&Bs[r][c] = *(const s16x8*)&A1T[(size_t)r * 512 + k0 + c];
    }
    __syncthreads();
#pragma unroll
    for (int kk = 0; kk < 2; ++kk) {
      const int kb_ = kk * 32 + hi * 8;
      s16x8 a = *(const s16x8*)&As[wm + l16][kb_];
#pragma unroll
      for (int j = 0; j < 2; ++j) {
        s16x8 b = *(const s16x8*)&Bs[wn + j * 16 + l16][kb_];
        accu[j] = __builtin_amdgcn_mfma_f32_16x16x32_bf16(a, b, accu[j], 0, 0, 0);
      }
    }
  }
  __syncthreads();
#pragma unroll
  for (int j = 0; j < 2; ++j)
#pragma unroll
    for (int i = 0; i < 4; ++i)
      Us[wm + hi * 4 + i][wn + j * 16 + l16] = f2bf(accu[j][i]);

  f32x4 w2a[2];
  w2a[0] = (f32x4){0.f, 0.f, 0.f, 0.f};
  w2a[1] = (f32x4){0.f, 0.f, 0.f, 0.f};
  for (int jc = 0; jc < 32; ++jc) {
#pragma unroll
    for (int i = 0; i < 2; ++i) {
      int idx = i * 256 + tid;
      int r = idx >> 3, c = (idx & 7) << 3;
      *(s16x8*)&B1s[r][c] = *(const s16x8*)&B1T[(size_t)(jc * 64 + r) * 64 + c];
      *(s16x8*)&A2s[r][c] = *(const s16x8*)&A2T[(size_t)r * 2048 + jc * 64 + c];
    }
    __syncthreads();
    f32x4 ha[2];
    ha[0] = (f32x4){0.f, 0.f, 0.f, 0.f};
    ha[1] = (f32x4){0.f, 0.f, 0.f, 0.f};
#pragma unroll
    for (int kk = 0; kk < 2; ++kk) {
      const int kb_ = kk * 32 + hi * 8;
      s16x8 a = *(const s16x8*)&Us[wm + l16][kb_];
#pragma unroll
      for (int j = 0; j < 2; ++j) {
        s16x8 b = *(const s16x8*)&B1s[wn + j * 16 + l16][kb_];
        ha[j] = __builtin_amdgcn_mfma_f32_16x16x32_bf16(a, b, ha[j], 0, 0, 0);
      }
    }
#pragma unroll
    for (int j = 0; j < 2; ++j)
#pragma unroll
      for (int i = 0; i < 4; ++i)
        Hs[wm + hi * 4 + i][wn + j * 16 + l16] = f2bf(fmaxf(ha[j][i], 0.f));
    __syncthreads();
#pragma unroll
    for (int kk = 0; kk < 2; ++kk) {
      const int kb_ = kk * 32 + hi * 8;
      s16x8 a = *(const s16x8*)&Hs[wm + l16][kb_];
#pragma unroll
      for (int j = 0; j < 2; ++j) {
        s16x8 b = *(const s16x8*)&A2s[wn + j * 16 + l16][kb_];
        w2a[j] = __builtin_amdgcn_mfma_f32_16x16x32_bf16(a, b, w2a[j], 0, 0, 0);
      }
    }
    __syncthreads();
  }
#pragma unroll
  for (int j = 0; j < 2; ++j)
#pragma unroll
    for (int i = 0; i < 4; ++i)
      w2[(size_t)(m0 + wm + hi * 4 + i) * 64 + wn + j * 16 + l16] = f2bf(w2a[j][i]);
}

// ---------------- host launch ----------------
extern "C" void kernel_launch(void* const* d_in, const int* in_sizes, int n_in,
                              void* d_out, int out_size, void* d_ws, size_t ws_size,
                              hipStream_t stream) {
  const float* q = (const float*)d_in[0];
  const float* k = (const float*)d_in[1];
  const float* v = (const float*)d_in[2];
  const float* Wq = (const float*)d_in[3];
  const float* bq = (const float*)d_in[4];
  const float* Wk = (const float*)d_in[5];
  const float* bk = (const float*)d_in[6];
  const float* Wv = (const float*)d_in[7];
  const float* bv = (const float*)d_in[8];
  const float* Wo = (const float*)d_in[9];
  const float* bo = (const float*)d_in[10];
  const float* topk = (const float*)d_in[11];
  const float* A1 = (const float*)d_in[12];
  const float* B1 = (const float*)d_in[13];
  const float* A2 = (const float*)d_in[14];
  const float* B2 = (const float*)d_in[15];
  const float* g1 = (const float*)d_in[16];
  const float* be1 = (const float*)d_in[17];
  const float* g2 = (const float*)d_in[18];
  const float* be2 = (const float*)d_in[19];

  char* ws = (char*)d_ws;
  constexpr size_t SZ_TOK_BF = (size_t)8192 * 512 * 2;
  constexpr size_t SZ_W_BF = (size_t)512 * 512 * 2;
  constexpr size_t O_QW = 0;
  constexpr size_t O_KW = O_QW + SZ_TOK_BF;
  constexpr size_t O_VW = O_KW + SZ_TOK_BF;
  constexpr size_t O_WQT = O_VW + SZ_TOK_BF;
  constexpr size_t O_WKT = O_WQT + SZ_W_BF;
  constexpr size_t O_WVT = O_WKT + SZ_W_BF;
  constexpr size_t O_WOT = O_WVT + SZ_W_BF;
  constexpr size_t O_A1T = O_WOT + SZ_W_BF;
  constexpr size_t O_B1T = O_A1T + 65536;
  constexpr size_t O_A2T = O_B1T + 262144;
  constexpr size_t O_B2T = O_A2T + 262144;
  constexpr size_t O_AO = O_B2T + 65536;
  constexpr size_t O_SRCB = O_AO + SZ_TOK_BF;
  constexpr size_t O_W2 = O_SRCB + SZ_TOK_BF;

  u16* Qw_ = (u16*)(ws + O_QW);
  u16* Kw_ = (u16*)(ws + O_KW);
  u16* Vw_ = (u16*)(ws + O_VW);
  u16* WqT = (u16*)(ws + O_WQT);
  u16* WkT = (u16*)(ws + O_WKT);
  u16* WvT = (u16*)(ws + O_WVT);
  u16* WoT = (u16*)(ws + O_WOT);
  u16* A1T = (u16*)(ws + O_A1T);
  u16* B1T = (u16*)(ws + O_B1T);
  u16* A2T = (u16*)(ws + O_A2T);
  u16* B2T = (u16*)(ws + O_B2T);
  u16* ao = (u16*)(ws + O_AO);
  u16* srcb = (u16*)(ws + O_SRCB);
  u16* w2 = (u16*)(ws + O_W2);

  // 1) weight transposes (f32->bf16)
  prep_w<<<5376, 256, 0, stream>>>(Wq, Wk, Wv, Wo, A1, B1, A2, B2,
                                   WqT, WkT, WvT, WoT, A1T, B1T, A2T, B2T);

  // 2) QKV projections straight from f32 inputs
  qkv_fused<<<dim3(4, 64, 3), 256, 0, stream>>>(q, k, v, WqT, WkT, WvT,
                                                bq, bk, bv, Qw_, Kw_, Vw_);

  // 3) fused attention
  attn_kernel<<<dim3(32, 64), 512, 0, stream>>>(Qw_, Kw_, Vw_, topk, ao);

  // 4) Wo + bias + residual(q) + LN1 -> srcb
  gemm_ln<true><<<512, 256, 0, stream>>>(ao, WoT, bo, q, nullptr, g1, be1, nullptr, srcb);

  // 5) fused FFN inner: w2 = relu(srcb@A1@B1)@A2
  ffn3<<<256, 256, 0, stream>>>(srcb, A1T, B1T, A2T, w2);

  // 6) B2 + residual(srcb) + LN2 -> d_out
  gemm_ln<false><<<512, 256, 0, stream>>>(w2, B2T, nullptr, nullptr, srcb, g2, be2,
                                          (float*)d_out, nullptr);
}